// Round 6
// baseline (77.675 us; speedup 1.0000x reference)
//
#include <hip/hip_runtime.h>
#include <stdint.h>

#define NSTRUCT 8
#define NROWS   1024
#define DD      128

typedef short bf16x8 __attribute__((ext_vector_type(8)));  // 8 bf16 (4 VGPRs)
typedef float f32x4  __attribute__((ext_vector_type(4)));  // 4 fp32 acc

// ---------------------------------------------------------------------------
// Threefry2x32-20, JAX partitionable path: bits = out0 ^ out1 (verified R2,
// absmax 0.0 vs jax reference). u = bitcast((bits>>9)|0x3f800000) - 1.0
// ---------------------------------------------------------------------------
__device__ __forceinline__ uint32_t rotl32(uint32_t x, uint32_t d) {
  return (x << d) | (x >> (32u - d));
}

__device__ __forceinline__ uint32_t threefry_bits(uint32_t i) {
  const uint32_t ks0 = 0u;
  const uint32_t ks1 = 42u;
  const uint32_t ks2 = 0x1BD11BDAu ^ ks0 ^ ks1;
  uint32_t x0 = 0u + ks0;   // counts_hi = 0
  uint32_t x1 = i  + ks1;   // counts_lo = flat (o,p,c) index
#define TF_RND(r) { x0 += x1; x1 = rotl32(x1, r); x1 ^= x0; }
  TF_RND(13) TF_RND(15) TF_RND(26) TF_RND(6)
  x0 += ks1; x1 += ks2 + 1u;
  TF_RND(17) TF_RND(29) TF_RND(16) TF_RND(24)
  x0 += ks2; x1 += ks0 + 2u;
  TF_RND(13) TF_RND(15) TF_RND(26) TF_RND(6)
  x0 += ks0; x1 += ks1 + 3u;
  TF_RND(17) TF_RND(29) TF_RND(16) TF_RND(24)
  x0 += ks1; x1 += ks2 + 4u;
  TF_RND(13) TF_RND(15) TF_RND(26) TF_RND(6)
  x0 += ks2; x1 += ks0 + 5u;
#undef TF_RND
  return x0 ^ x1;
}

__device__ __forceinline__ uint16_t f32_to_bf16_rne(float v) {
  uint32_t fb = __float_as_uint(v);
  uint32_t lsb = (fb >> 16) & 1u;
  return (uint16_t)((fb + 0x7fffu + lsb) >> 16);
}

// truncation-pack two fp32 -> one dword of two bf16 (lo in low half)
__device__ __forceinline__ uint32_t pk_bf16_trunc(float lo, float hi) {
  return __builtin_amdgcn_perm(__float_as_uint(hi), __float_as_uint(lo),
                               0x07060302u);
}

// ---------------------------------------------------------------------------
// Single fused kernel. Grid: 8 structs x 8 col-tiles = 64 blocks, 512 thr.
// Phase A: block's disjoint M slice (K=128 x 16 cols) -> Threefry (4/thread,
//          zero global redundancy) -> bf16 B-fragments in 4 KB LDS.
// Phase B: each wave loads its 4 B-frags (b128, conflict-free).
// Phase C: wave w sweeps rows w*128..+127 in 16-row tiles: A-frags converted
//          inline from fp32 x via v_perm truncation-pack, 4 MFMA per tile
//          (16x16x32 bf16), C stored per verified layout
//          (row=(lane>>4)*4+reg, col=lane&15).
// No d_ws use, no second kernel, one barrier.
// ---------------------------------------------------------------------------
__global__ __launch_bounds__(512, 1) void nnl0_fused(
    const float* __restrict__ x,
    const float* __restrict__ maskings,
    const float* __restrict__ theta,
    const float* __restrict__ W,
    float* __restrict__ out) {
  __shared__ uint16_t Bf[2048];   // 4 KB: [kk(4)][lane(64)][j(8)] bf16

  const int b   = blockIdx.x;
  const int o   = b >> 3;          // structure 0..7
  const int ct  = b & 7;           // 16-col tile 0..7
  const int tid = threadIdx.x;
  const int w    = tid >> 6;       // wave 0..7
  const int lane = tid & 63;

  // ---- Phase A: build B-fragments for this (o, ct) slice ----
#pragma unroll
  for (int s = 0; s < 4; ++s) {
    int f    = s * 512 + tid;            // 0..2047
    int j    = f & 7;
    int lf   = (f >> 3) & 63;
    int kk   = f >> 9;
    int p    = kk * 32 + ((lf >> 4) << 3) + j;   // K index 0..127
    int c    = (ct << 4) + (lf & 15);            // col 0..127
    int gi   = (o << 14) + (p << 7) + c;         // flat (o,p,c)
    uint32_t bits = threefry_bits((uint32_t)gi);
    float u = __uint_as_float((bits >> 9) | 0x3f800000u) - 1.0f;
    float v = (u < theta[gi]) ? maskings[gi] * W[gi] : 0.0f;
    Bf[f] = f32_to_bf16_rne(v);
  }
  __syncthreads();

  // ---- Phase B: per-wave B-frag registers ----
  const bf16x8* bfv = (const bf16x8*)Bf;
  bf16x8 bfrag[4];
#pragma unroll
  for (int kk = 0; kk < 4; ++kk) bfrag[kk] = bfv[kk * 64 + lane];

  // ---- Phase C: sweep 128 rows per wave, 8 tiles of 16 ----
  const int kq   = (lane >> 4) << 3;   // k sub-offset 0,8,16,24
  const int mloc = lane & 15;          // row-in-tile for A, col for C
  const int rq   = (lane >> 4) << 2;   // C row quad base

#pragma unroll
  for (int i = 0; i < 8; ++i) {
    const int nb = (w << 7) + (i << 4);          // tile row base
    const float* xr = x + (size_t)(nb + mloc) * DD + kq;

    f32x4 acc = {0.f, 0.f, 0.f, 0.f};
#pragma unroll
    for (int kk = 0; kk < 4; ++kk) {
      float4 q0 = *(const float4*)(xr + kk * 32);
      float4 q1 = *(const float4*)(xr + kk * 32 + 4);
      union { bf16x8 v; uint32_t u[4]; } af;
      af.u[0] = pk_bf16_trunc(q0.x, q0.y);
      af.u[1] = pk_bf16_trunc(q0.z, q0.w);
      af.u[2] = pk_bf16_trunc(q1.x, q1.y);
      af.u[3] = pk_bf16_trunc(q1.z, q1.w);
      acc = __builtin_amdgcn_mfma_f32_16x16x32_bf16(af.v, bfrag[kk], acc, 0, 0, 0);
    }

    float* obase = out + ((size_t)o * NROWS + nb + rq) * DD + (ct << 4) + mloc;
#pragma unroll
    for (int r = 0; r < 4; ++r) obase[(size_t)r * DD] = acc[r];
  }
}

// ---------------------------------------------------------------------------

extern "C" void kernel_launch(void* const* d_in, const int* in_sizes, int n_in,
                              void* d_out, int out_size, void* d_ws, size_t ws_size,
                              hipStream_t stream) {
  const float* x        = (const float*)d_in[0];
  const float* maskings = (const float*)d_in[1];
  const float* theta    = (const float*)d_in[2];
  const float* W        = (const float*)d_in[3];
  float* out = (float*)d_out;

  nnl0_fused<<<NSTRUCT * 8, 512, 0, stream>>>(x, maskings, theta, W, out);
}

// Round 7
// 68.354 us; speedup vs baseline: 1.1364x; 1.1364x over previous
//
#include <hip/hip_runtime.h>
#include <stdint.h>

#define NSTRUCT 8
#define NROWS   1024
#define DD      128

typedef short bf16x8 __attribute__((ext_vector_type(8)));  // 8 bf16 (4 VGPRs)
typedef float f32x4  __attribute__((ext_vector_type(4)));  // 4 fp32 acc

// ---------------------------------------------------------------------------
// Threefry2x32-20, JAX partitionable path: bits = out0 ^ out1 (verified R2,
// absmax 0.0 vs jax reference). u = bitcast((bits>>9)|0x3f800000) - 1.0
// ---------------------------------------------------------------------------
__device__ __forceinline__ uint32_t rotl32(uint32_t x, uint32_t d) {
  return (x << d) | (x >> (32u - d));
}

__device__ __forceinline__ uint32_t threefry_bits(uint32_t i) {
  const uint32_t ks0 = 0u;
  const uint32_t ks1 = 42u;
  const uint32_t ks2 = 0x1BD11BDAu ^ ks0 ^ ks1;
  uint32_t x0 = 0u + ks0;   // counts_hi = 0
  uint32_t x1 = i  + ks1;   // counts_lo = flat (o,p,c) index
#define TF_RND(r) { x0 += x1; x1 = rotl32(x1, r); x1 ^= x0; }
  TF_RND(13) TF_RND(15) TF_RND(26) TF_RND(6)
  x0 += ks1; x1 += ks2 + 1u;
  TF_RND(17) TF_RND(29) TF_RND(16) TF_RND(24)
  x0 += ks2; x1 += ks0 + 2u;
  TF_RND(13) TF_RND(15) TF_RND(26) TF_RND(6)
  x0 += ks0; x1 += ks1 + 3u;
  TF_RND(17) TF_RND(29) TF_RND(16) TF_RND(24)
  x0 += ks1; x1 += ks2 + 4u;
  TF_RND(13) TF_RND(15) TF_RND(26) TF_RND(6)
  x0 += ks2; x1 += ks0 + 5u;
#undef TF_RND
  return x0 ^ x1;
}

__device__ __forceinline__ uint16_t f32_to_bf16_rne(float v) {
  uint32_t fb = __float_as_uint(v);
  uint32_t lsb = (fb >> 16) & 1u;
  return (uint16_t)((fb + 0x7fffu + lsb) >> 16);
}

// truncation-pack two fp32 -> one dword of two bf16 (lo in low half)
__device__ __forceinline__ uint32_t pk_bf16_trunc(float lo, float hi) {
  return __builtin_amdgcn_perm(__float_as_uint(hi), __float_as_uint(lo),
                               0x07060302u);
}

// ---------------------------------------------------------------------------
// Single fused kernel, wide grid. 8 o x 8 ct x 8 rg = 512 blocks, 256 thr
// (2 blocks/CU). Per block: (o, 16-col tile, 128-row group).
//   1. Issue ALL x global loads (16 float4/thread) -- in flight during...
//   2. Threefry phase: 8 draws/thread -> bf16 B-frags for (o,ct) in 4 KB LDS.
//   3. One barrier; read 4 B-frags/wave from LDS (b128, conflict-free).
//   4. Per wave: 2 row-tiles x 4 MFMA (16x16x32 bf16), x packed to bf16 via
//      v_perm truncation (same numerics as R5/R6, absmax 0.125).
// C/D layout (verified): row=(lane>>4)*4+reg, col=lane&15.
// ---------------------------------------------------------------------------
__global__ __launch_bounds__(256, 2) void nnl0_fused(
    const float* __restrict__ x,
    const float* __restrict__ maskings,
    const float* __restrict__ theta,
    const float* __restrict__ W,
    float* __restrict__ out) {
  __shared__ uint16_t Bf[2048];   // 4 KB: [kk(4)][lane(64)][j(8)] bf16

  const int b    = blockIdx.x;
  const int o    = b >> 6;         // structure 0..7
  const int ct   = (b >> 3) & 7;   // 16-col tile 0..7
  const int rg   = b & 7;          // 128-row group 0..7
  const int tid  = threadIdx.x;
  const int w    = tid >> 6;       // wave 0..3
  const int lane = tid & 63;

  const int kq   = (lane >> 4) << 3;   // k sub-offset 0,8,16,24
  const int mloc = lane & 15;          // row-in-tile for A, col for C
  const int rq   = (lane >> 4) << 2;   // C row quad base

  // ---- 1. issue x loads for both tiles up front (latency hidden by PRNG) --
  float4 xq[2][4][2];
#pragma unroll
  for (int i = 0; i < 2; ++i) {
    const int nb = (rg << 7) + (w << 5) + (i << 4);   // tile row base
    const float* xr = x + (size_t)(nb + mloc) * DD + kq;
#pragma unroll
    for (int kk = 0; kk < 4; ++kk) {
      xq[i][kk][0] = *(const float4*)(xr + kk * 32);
      xq[i][kk][1] = *(const float4*)(xr + kk * 32 + 4);
    }
  }

  // ---- 2. Threefry: build B-fragments for this (o, ct) slice ----
#pragma unroll
  for (int s = 0; s < 8; ++s) {
    int f  = s * 256 + tid;              // 0..2047 frag-flat
    int j  = f & 7;
    int lf = (f >> 3) & 63;
    int kk = f >> 9;
    int p  = kk * 32 + ((lf >> 4) << 3) + j;   // K index 0..127
    int c  = (ct << 4) + (lf & 15);            // col 0..127
    int gi = (o << 14) + (p << 7) + c;         // flat (o,p,c)
    uint32_t bits = threefry_bits((uint32_t)gi);
    float u = __uint_as_float((bits >> 9) | 0x3f800000u) - 1.0f;
    float v = (u < theta[gi]) ? maskings[gi] * W[gi] : 0.0f;
    Bf[f] = f32_to_bf16_rne(v);
  }
  __syncthreads();

  // ---- 3. per-wave B-frag registers ----
  const bf16x8* bfv = (const bf16x8*)Bf;
  bf16x8 bfrag[4];
#pragma unroll
  for (int kk = 0; kk < 4; ++kk) bfrag[kk] = bfv[kk * 64 + lane];

  // ---- 4. two 16-row tiles per wave ----
#pragma unroll
  for (int i = 0; i < 2; ++i) {
    const int nb = (rg << 7) + (w << 5) + (i << 4);
    f32x4 acc = {0.f, 0.f, 0.f, 0.f};
#pragma unroll
    for (int kk = 0; kk < 4; ++kk) {
      union { bf16x8 v; uint32_t u[4]; } af;
      af.u[0] = pk_bf16_trunc(xq[i][kk][0].x, xq[i][kk][0].y);
      af.u[1] = pk_bf16_trunc(xq[i][kk][0].z, xq[i][kk][0].w);
      af.u[2] = pk_bf16_trunc(xq[i][kk][1].x, xq[i][kk][1].y);
      af.u[3] = pk_bf16_trunc(xq[i][kk][1].z, xq[i][kk][1].w);
      acc = __builtin_amdgcn_mfma_f32_16x16x32_bf16(af.v, bfrag[kk], acc, 0, 0, 0);
    }
    float* obase = out + ((size_t)o * NROWS + nb + rq) * DD + (ct << 4) + mloc;
#pragma unroll
    for (int r = 0; r < 4; ++r) obase[(size_t)r * DD] = acc[r];
  }
}

// ---------------------------------------------------------------------------

extern "C" void kernel_launch(void* const* d_in, const int* in_sizes, int n_in,
                              void* d_out, int out_size, void* d_ws, size_t ws_size,
                              hipStream_t stream) {
  const float* x        = (const float*)d_in[0];
  const float* maskings = (const float*)d_in[1];
  const float* theta    = (const float*)d_in[2];
  const float* W        = (const float*)d_in[3];
  float* out = (float*)d_out;

  nnl0_fused<<<NSTRUCT * 8 * 8, 256, 0, stream>>>(x, maskings, theta, W, out);
}

// Round 8
// 65.382 us; speedup vs baseline: 1.1880x; 1.0454x over previous
//
#include <hip/hip_runtime.h>
#include <stdint.h>

#define NSTRUCT 8
#define NROWS   1024
#define DD      128

typedef short bf16x8 __attribute__((ext_vector_type(8)));  // 8 bf16 (4 VGPRs)
typedef float f32x4  __attribute__((ext_vector_type(4)));  // 4 fp32 acc

// ---------------------------------------------------------------------------
// Threefry2x32-20, JAX partitionable path: bits = out0 ^ out1 (verified R2,
// absmax 0.0 vs jax reference). u = bitcast((bits>>9)|0x3f800000) - 1.0
// ---------------------------------------------------------------------------
__device__ __forceinline__ uint32_t rotl32(uint32_t x, uint32_t d) {
  return (x << d) | (x >> (32u - d));
}

__device__ __forceinline__ uint32_t threefry_bits(uint32_t i) {
  const uint32_t ks0 = 0u;
  const uint32_t ks1 = 42u;
  const uint32_t ks2 = 0x1BD11BDAu ^ ks0 ^ ks1;
  uint32_t x0 = 0u + ks0;   // counts_hi = 0
  uint32_t x1 = i  + ks1;   // counts_lo = flat (o,p,c) index
#define TF_RND(r) { x0 += x1; x1 = rotl32(x1, r); x1 ^= x0; }
  TF_RND(13) TF_RND(15) TF_RND(26) TF_RND(6)
  x0 += ks1; x1 += ks2 + 1u;
  TF_RND(17) TF_RND(29) TF_RND(16) TF_RND(24)
  x0 += ks2; x1 += ks0 + 2u;
  TF_RND(13) TF_RND(15) TF_RND(26) TF_RND(6)
  x0 += ks0; x1 += ks1 + 3u;
  TF_RND(17) TF_RND(29) TF_RND(16) TF_RND(24)
  x0 += ks1; x1 += ks2 + 4u;
  TF_RND(13) TF_RND(15) TF_RND(26) TF_RND(6)
  x0 += ks2; x1 += ks0 + 5u;
#undef TF_RND
  return x0 ^ x1;
}

__device__ __forceinline__ uint16_t f32_to_bf16_rne(float v) {
  uint32_t fb = __float_as_uint(v);
  uint32_t lsb = (fb >> 16) & 1u;
  return (uint16_t)((fb + 0x7fffu + lsb) >> 16);
}

// ---------------------------------------------------------------------------
// build_frags: 256 blocks x 256 thr, 4 fragment elements/thread, dwordx2
// stores. Blocks 0..127: M (Threefry+mask, RNE->bf16) in B-frag order;
// blocks 128..255: x (RNE->bf16) in A-frag order (float4 source loads).
// Fragment layouts (16x16x32 bf16, m89/m120-verified):
//   A: lane holds A[m=lane&15][k=(lane>>4)*8+j]
//   B: lane holds B[k=(lane>>4)*8+j][n=lane&15]
// Mb layout: [o(8)][ct(8)][kk(4)][lane(64)][j(8)]  256 KB
// xb layout: [rt(64)][kk(4)][lane(64)][j(8)]       256 KB
// ---------------------------------------------------------------------------
__global__ __launch_bounds__(256) void build_frags(
    const float* __restrict__ x,
    const float* __restrict__ maskings,
    const float* __restrict__ theta,
    const float* __restrict__ W,
    uint16_t* __restrict__ Mb,
    uint16_t* __restrict__ xb) {
  const int b = blockIdx.x;
  const int tid = threadIdx.x;
  if (b < 128) {
    // M fragments: 4 consecutive elements f0..f0+3 (same lane, j0=0 or 4)
    uint32_t t    = (uint32_t)b * 256u + tid;   // 0..32767
    uint32_t f0   = t << 2;
    uint32_t j0   = f0 & 7u;
    uint32_t lane = (f0 >> 3) & 63u;
    uint32_t kk   = (f0 >> 9) & 3u;
    uint32_t ct   = (f0 >> 11) & 7u;
    uint32_t o    = f0 >> 14;
    uint32_t p0   = kk * 32u + (lane >> 4) * 8u + j0;  // K index base
    uint32_t c    = ct * 16u + (lane & 15u);           // N index
    uint32_t gi0  = (o << 14) | (p0 << 7) | c;         // flat (o,p,c)
    ushort4 pk;
    uint16_t* pkp = (uint16_t*)&pk;
#pragma unroll
    for (int e = 0; e < 4; ++e) {
      uint32_t gi = gi0 + (uint32_t)e * 128u;          // p+1 => +DD
      uint32_t bits = threefry_bits(gi);
      float u = __uint_as_float((bits >> 9) | 0x3f800000u) - 1.0f;
      float v = (u < theta[gi]) ? maskings[gi] * W[gi] : 0.0f;
      pkp[e] = f32_to_bf16_rne(v);
    }
    *(ushort4*)(Mb + f0) = pk;
  } else {
    // x fragments: 4 consecutive elements = 4 consecutive k -> float4 load
    uint32_t t    = (uint32_t)(b - 128) * 256u + tid;  // 0..32767
    uint32_t f0   = t << 2;
    uint32_t j0   = f0 & 7u;
    uint32_t lane = (f0 >> 3) & 63u;
    uint32_t kk   = (f0 >> 9) & 3u;
    uint32_t rt   = f0 >> 11;                          // 16-row tile 0..63
    uint32_t n    = rt * 16u + (lane & 15u);
    uint32_t k0   = kk * 32u + (lane >> 4) * 8u + j0;  // aligned to 4
    float4 v = *(const float4*)&x[n * DD + k0];
    ushort4 pk;
    pk.x = f32_to_bf16_rne(v.x);
    pk.y = f32_to_bf16_rne(v.y);
    pk.z = f32_to_bf16_rne(v.z);
    pk.w = f32_to_bf16_rne(v.w);
    *(ushort4*)(xb + f0) = pk;
  }
}

// ---------------------------------------------------------------------------
// sem_mfma (unchanged from R5, proven 62.6 us config):
// out[o,n,c] = sum_p x[n,p] * M[o,p,c] via 16x16x32 bf16 MFMA, fp32 accum.
// Grid: 8 structs x 32 row-blocks = 256 blocks x 256 thr (4 waves).
// No LDS, no barrier; fragments straight from global (L2-resident).
// C/D layout (verified): row=(lane>>4)*4+reg, col=lane&15.
// ---------------------------------------------------------------------------
__global__ __launch_bounds__(256) void sem_mfma(
    const uint16_t* __restrict__ Mb,
    const uint16_t* __restrict__ xb,
    float* __restrict__ out) {
  const int bidx = blockIdx.x;
  const int o    = bidx >> 5;        // structure 0..7
  const int rb   = bidx & 31;        // 32-row block
  const int tid  = threadIdx.x;
  const int w    = tid >> 6;         // wave 0..3
  const int lane = tid & 63;
  const int rt_g = rb * 2 + (w & 1); // global 16-row tile 0..63
  const int ctb  = (w >> 1) * 4;     // col-tile base 0 or 4

  const bf16x8* xbv = (const bf16x8*)xb;
  const bf16x8* mbv = (const bf16x8*)Mb;

  bf16x8 a[4];
#pragma unroll
  for (int kk = 0; kk < 4; ++kk) a[kk] = xbv[(rt_g * 4 + kk) * 64 + lane];

  f32x4 acc[4] = {{0.f, 0.f, 0.f, 0.f}, {0.f, 0.f, 0.f, 0.f},
                  {0.f, 0.f, 0.f, 0.f}, {0.f, 0.f, 0.f, 0.f}};

#pragma unroll
  for (int t = 0; t < 4; ++t) {
    const int ct = ctb + t;
#pragma unroll
    for (int kk = 0; kk < 4; ++kk) {
      bf16x8 bfrag = mbv[((o * 8 + ct) * 4 + kk) * 64 + lane];
      acc[t] = __builtin_amdgcn_mfma_f32_16x16x32_bf16(a[kk], bfrag, acc[t], 0, 0, 0);
    }
  }

  const int col0     = lane & 15;
  const int row_base = rb * 32 + (w & 1) * 16 + (lane >> 4) * 4;
#pragma unroll
  for (int t = 0; t < 4; ++t) {
    const int col = (ctb + t) * 16 + col0;
#pragma unroll
    for (int r = 0; r < 4; ++r) {
      out[((size_t)o * NROWS + row_base + r) * DD + col] = acc[t][r];
    }
  }
}

// ---------------------------------------------------------------------------

extern "C" void kernel_launch(void* const* d_in, const int* in_sizes, int n_in,
                              void* d_out, int out_size, void* d_ws, size_t ws_size,
                              hipStream_t stream) {
  const float* x        = (const float*)d_in[0];
  const float* maskings = (const float*)d_in[1];
  const float* theta    = (const float*)d_in[2];
  const float* W        = (const float*)d_in[3];
  float* out = (float*)d_out;

  uint16_t* Mb = (uint16_t*)d_ws;          // 256 KB (B-frag order)
  uint16_t* xb = Mb + NSTRUCT * DD * DD;   // 256 KB (A-frag order)

  build_frags<<<256, 256, 0, stream>>>(x, maskings, theta, W, Mb, xb);
  sem_mfma<<<NSTRUCT * 32, 256, 0, stream>>>(Mb, xb, out);
}